// Round 2
// baseline (805.155 us; speedup 1.0000x reference)
//
#include <hip/hip_runtime.h>

// ---------------------------------------------------------------------------
// MultiHead_BlockAttention: out[b,s,h*512+d] = softmax(X M_h X^T) (X Wv_h)
//   M'_h = Wk_h Wq_h^T (per head), T_h = X M'_h^T, logits = T X^T.
// Precision: bf16 hi/lo x3-split on the logit path; plain bf16 for V/P.
// R2: fused logits+softmax+PV flash kernel (T read once, no LOG/P in HBM),
//     L2-locality grid reorders for T-GEMM and VT-GEMM.
// ---------------------------------------------------------------------------

typedef unsigned short u16;
typedef __bf16 bf16x8 __attribute__((ext_vector_type(8)));
typedef unsigned short u16x4 __attribute__((ext_vector_type(4)));
typedef float f32x4 __attribute__((ext_vector_type(4)));

typedef __attribute__((address_space(1))) void gvoid_t;
typedef __attribute__((address_space(3))) void svoid_t;

__device__ __forceinline__ u16 f2bf(float f) {
  unsigned u = __float_as_uint(f);
  u = (u + 0x7fffu + ((u >> 16) & 1u)) >> 16;  // RTN-even
  return (u16)u;
}
__device__ __forceinline__ float bf2f(u16 h) {
  return __uint_as_float(((unsigned)h) << 16);
}

__device__ __forceinline__ f32x4 mfma16(bf16x8 a, bf16x8 b, f32x4 c) {
  return __builtin_amdgcn_mfma_f32_16x16x32_bf16(a, b, c, 0, 0, 0);
}

// ---------------- prep: fp32 -> bf16 hi/lo split (same layout) -------------
__global__ __launch_bounds__(256) void split_hl_kernel(
    const float* __restrict__ in, u16* __restrict__ hi, u16* __restrict__ lo,
    int n4) {
  int i = blockIdx.x * 256 + threadIdx.x;
  if (i >= n4) return;
  float4 v = ((const float4*)in)[i];
  float vv[4] = {v.x, v.y, v.z, v.w};
  u16x4 h, l;
#pragma unroll
  for (int j = 0; j < 4; ++j) {
    u16 hh = f2bf(vv[j]);
    h[j] = hh;
    l[j] = f2bf(vv[j] - bf2f(hh));
  }
  ((u16x4*)hi)[i] = h;
  ((u16x4*)lo)[i] = l;
}

// ---------------- prep: transpose [512,4096] -> [4096,512] + split ---------
__global__ __launch_bounds__(256) void transpose_split_w(
    const float* __restrict__ in, u16* __restrict__ hi, u16* __restrict__ lo) {
  __shared__ float t[32][33];
  int d0 = blockIdx.x * 32, f0 = blockIdx.y * 32;
  int tx = threadIdx.x, ty = threadIdx.y;  // blockDim = (32,8)
#pragma unroll
  for (int r = 0; r < 4; ++r)
    t[ty + r * 8][tx] = in[(size_t)(f0 + ty + r * 8) * 4096 + d0 + tx];
  __syncthreads();
#pragma unroll
  for (int r = 0; r < 4; ++r) {
    float v = t[tx][ty + r * 8];  // = in[f0+tx][d0+ty+r*8]
    int d = d0 + ty + r * 8, f = f0 + tx;
    u16 h = f2bf(v);
    size_t idx = (size_t)d * 512 + f;
    hi[idx] = h;
    lo[idx] = f2bf(v - bf2f(h));
  }
}

// ---------------- LDS staging helpers (XOR-swizzled 16B chunks) ------------
// tile layout [rows][32 k] bf16; chunk (m,cq) stored at col c' = cq^((m>>1)&3)
__device__ __forceinline__ void stage_tile(u16* ldsTile, const u16* g0, int ld,
                                           int wave, int lane) {
#pragma unroll
  for (int r = 0; r < 2; ++r) {
    int p = r * 256 + wave * 64 + lane;  // LDS chunk position (128 rows x 4)
    int m = p >> 2;
    int cq = (p & 3) ^ ((m >> 1) & 3);   // global chunk col
    const u16* g = g0 + (size_t)m * ld + cq * 8;
    u16* l = ldsTile + (size_t)(r * 256 + wave * 64) * 8;  // wave-uniform
    __builtin_amdgcn_global_load_lds((gvoid_t*)g, (svoid_t*)l, 16, 0, 0);
  }
}

__device__ __forceinline__ void stage64(u16* ldsTile, const u16* g0, int ld,
                                        int wave, int lane) {
  int p = wave * 64 + lane;  // 64 rows x 4 chunks = 256
  int m = p >> 2;
  int cq = (p & 3) ^ ((m >> 1) & 3);
  const u16* g = g0 + (size_t)m * ld + cq * 8;
  u16* l = ldsTile + (size_t)(wave * 64) * 8;
  __builtin_amdgcn_global_load_lds((gvoid_t*)g, (svoid_t*)l, 16, 0, 0);
}

__device__ __forceinline__ bf16x8 ldsfrag(const u16* tile, int row, int quad) {
  int c = quad ^ ((row >> 1) & 3);
  return *(const bf16x8*)(tile + row * 32 + c * 8);
}

// ---------------- GEMM core: C[m][n] = sum_k A[m][k] * B[n][k] -------------
// GRID 0: (x=n0, y=m0, z=hb16) legacy; GRID 1: (x=n0, y=head, z=m0);
// GRID 2: (x=m0, y=n0). OMODE: 0 fp32; 1 bf16; 2 hi/lo bf16.
template <int SPLIT, int OMODE, int GRID>
__global__ __launch_bounds__(256, 2) void gemm_bt(
    const u16* __restrict__ Ah, const u16* __restrict__ Al,
    const u16* __restrict__ Bh, const u16* __restrict__ Bl,
    void* __restrict__ C0, void* __restrict__ C1, int lda, int ldb, int ldc,
    int K, size_t aH, size_t aB, size_t bH, size_t bB, size_t cH, size_t cB) {
  __shared__ __align__(16) u16 lds[(SPLIT ? 4 : 2) * 4096];
  u16* lAh = lds;
  u16* lAl = SPLIT ? (lds + 4096) : lds;
  u16* lBh = lds + (SPLIT ? 8192 : 4096);
  u16* lBl = SPLIT ? (lds + 12288) : lds;

  int m0, n0;
  size_t aOff, bOff, cOff;
  if (GRID == 0) {
    int zh = blockIdx.z >> 4, zb = blockIdx.z & 15;
    m0 = blockIdx.y * 128;
    n0 = blockIdx.x * 128;
    aOff = zh * aH + zb * aB;
    bOff = zh * bH + zb * bB;
    cOff = zh * cH + zb * cB;
  } else if (GRID == 1) {
    m0 = blockIdx.z * 128;
    n0 = blockIdx.x * 128;
    aOff = 0;
    bOff = blockIdx.y * bH;
    cOff = blockIdx.y * cH;
  } else {
    m0 = blockIdx.x * 128;
    n0 = blockIdx.y * 128;
    aOff = 0;
    bOff = 0;
    cOff = 0;
  }
  Ah += aOff;
  Al += aOff;
  Bh += bOff;
  Bl += bOff;

  const int tid = threadIdx.x;
  const int wave = tid >> 6, lane = tid & 63;
  const int quad = lane >> 4, l16 = lane & 15;
  const int wm = (wave >> 1) * 64, wn = (wave & 1) * 64;

  f32x4 acc[4][4] = {};

  for (int k0 = 0; k0 < K; k0 += 32) {
    stage_tile(lAh, Ah + (size_t)m0 * lda + k0, lda, wave, lane);
    if (SPLIT) stage_tile(lAl, Al + (size_t)m0 * lda + k0, lda, wave, lane);
    stage_tile(lBh, Bh + (size_t)n0 * ldb + k0, ldb, wave, lane);
    if (SPLIT) stage_tile(lBl, Bl + (size_t)n0 * ldb + k0, ldb, wave, lane);
    __syncthreads();

    bf16x8 a_h[4], a_l[4], b_h[4], b_l[4];
#pragma unroll
    for (int i = 0; i < 4; ++i) {
      a_h[i] = ldsfrag(lAh, wm + i * 16 + l16, quad);
      b_h[i] = ldsfrag(lBh, wn + i * 16 + l16, quad);
      if (SPLIT) {
        a_l[i] = ldsfrag(lAl, wm + i * 16 + l16, quad);
        b_l[i] = ldsfrag(lBl, wn + i * 16 + l16, quad);
      }
    }
#pragma unroll
    for (int i = 0; i < 4; ++i)
#pragma unroll
      for (int j = 0; j < 4; ++j) {
        acc[i][j] = mfma16(a_h[i], b_h[j], acc[i][j]);
        if (SPLIT) {
          acc[i][j] = mfma16(a_h[i], b_l[j], acc[i][j]);
          acc[i][j] = mfma16(a_l[i], b_h[j], acc[i][j]);
        }
      }
    __syncthreads();
  }

  // epilogue: C/D layout col = lane&15, row = quad*4 + reg
#pragma unroll
  for (int i = 0; i < 4; ++i) {
#pragma unroll
    for (int j = 0; j < 4; ++j) {
      int col = n0 + wn + j * 16 + l16;
#pragma unroll
      for (int r = 0; r < 4; ++r) {
        int row = m0 + wm + i * 16 + quad * 4 + r;
        size_t idx = cOff + (size_t)row * ldc + col;
        float v = acc[i][j][r];
        if (OMODE == 0) {
          ((float*)C0)[idx] = v;
        } else if (OMODE == 1) {
          ((u16*)C0)[idx] = f2bf(v);
        } else {
          u16 h = f2bf(v);
          ((u16*)C0)[idx] = h;
          ((u16*)C1)[idx] = f2bf(v - bf2f(h));
        }
      }
    }
  }
}

// ---------------- fused logits + softmax + PV (flash-style) ----------------
// Block = (q-tile 64 rows, one (h,b)). 4 waves; wave w owns key/dim slice
// [w*128, w*128+128). S = T X^T (x3 split) in 4x8 acc frags; cross-wave
// row max/sum via LDS; P chunked 16KB through LDS into PV (V staged 32KB/k).
__global__ __launch_bounds__(256, 2) void attn_fused(
    const u16* __restrict__ Th, const u16* __restrict__ Tl,
    const u16* __restrict__ Xh, const u16* __restrict__ Xl,
    const u16* __restrict__ Vt, float* __restrict__ out) {
  __shared__ __align__(16) u16 lds[36864];  // 72KB
  __shared__ float red[4][64];
  const int q0 = blockIdx.x * 64;
  const int h = blockIdx.y >> 4, b = blockIdx.y & 15;
  const int tid = threadIdx.x, wave = tid >> 6, lane = tid & 63;
  const int quad = lane >> 4, l16 = lane & 15;

  const u16* Ath =
      Th + (size_t)h * 4194304 + (size_t)b * 262144 + (size_t)q0 * 512;
  const u16* Atl =
      Tl + (size_t)h * 4194304 + (size_t)b * 262144 + (size_t)q0 * 512;
  const u16* Bxh = Xh + (size_t)b * 262144;
  const u16* Bxl = Xl + (size_t)b * 262144;
  const u16* Vb = Vt + (size_t)h * 512 * 8192 + (size_t)b * 512;

  u16* lAh = lds;          // 2048 u16 (4KB)
  u16* lAl = lds + 2048;   // 4KB
  u16* lBh = lds + 4096;   // 16384 u16 (32KB)
  u16* lBl = lds + 20480;  // 32KB

  f32x4 acc[4][8] = {};

  // ---- phase S: logits ----
  for (int k0 = 0; k0 < 512; k0 += 32) {
    stage64(lAh, Ath + k0, 512, wave, lane);
    stage64(lAl, Atl + k0, 512, wave, lane);
#pragma unroll
    for (int g = 0; g < 4; ++g) {
      stage_tile(lBh + g * 4096, Bxh + (size_t)(g * 128) * 512 + k0, 512, wave,
                 lane);
      stage_tile(lBl + g * 4096, Bxl + (size_t)(g * 128) * 512 + k0, 512, wave,
                 lane);
    }
    __syncthreads();
    bf16x8 a_h[4], a_l[4];
#pragma unroll
    for (int i = 0; i < 4; ++i) {
      a_h[i] = ldsfrag(lAh, i * 16 + l16, quad);
      a_l[i] = ldsfrag(lAl, i * 16 + l16, quad);
    }
#pragma unroll
    for (int j = 0; j < 8; ++j) {
      int br = wave * 128 + j * 16 + l16;
      bf16x8 b_h = ldsfrag(lBh, br, quad);
      bf16x8 b_l = ldsfrag(lBl, br, quad);
#pragma unroll
      for (int i = 0; i < 4; ++i) {
        acc[i][j] = mfma16(a_h[i], b_h, acc[i][j]);
        acc[i][j] = mfma16(a_h[i], b_l, acc[i][j]);
        acc[i][j] = mfma16(a_l[i], b_h, acc[i][j]);
      }
    }
    __syncthreads();
  }

  // ---- softmax over full rows (512 cols across the 4 waves) ----
  // lane's rows: i*16 + quad*4 + r ; cols: wave*128 + j*16 + l16
  float mx[4][4];
#pragma unroll
  for (int i = 0; i < 4; ++i)
#pragma unroll
    for (int r = 0; r < 4; ++r) {
      float m = acc[i][0][r];
#pragma unroll
      for (int j = 1; j < 8; ++j) m = fmaxf(m, acc[i][j][r]);
#pragma unroll
      for (int o = 1; o < 16; o <<= 1) m = fmaxf(m, __shfl_xor(m, o));
      mx[i][r] = m;
    }
  if (l16 == 0) {
#pragma unroll
    for (int i = 0; i < 4; ++i)
#pragma unroll
      for (int r = 0; r < 4; ++r) red[wave][i * 16 + quad * 4 + r] = mx[i][r];
  }
  __syncthreads();
#pragma unroll
  for (int i = 0; i < 4; ++i)
#pragma unroll
    for (int r = 0; r < 4; ++r) {
      int row = i * 16 + quad * 4 + r;
      mx[i][r] = fmaxf(fmaxf(red[0][row], red[1][row]),
                       fmaxf(red[2][row], red[3][row]));
    }
  __syncthreads();  // red reads done before sum round reuses it
  float sm[4][4];
#pragma unroll
  for (int i = 0; i < 4; ++i)
#pragma unroll
    for (int r = 0; r < 4; ++r) {
      float s = 0.f;
#pragma unroll
      for (int j = 0; j < 8; ++j) {
        float e = __expf(acc[i][j][r] - mx[i][r]);
        acc[i][j][r] = e;
        s += e;
      }
#pragma unroll
      for (int o = 1; o < 16; o <<= 1) s += __shfl_xor(s, o);
      sm[i][r] = s;
    }
  if (l16 == 0) {
#pragma unroll
    for (int i = 0; i < 4; ++i)
#pragma unroll
      for (int r = 0; r < 4; ++r) red[wave][i * 16 + quad * 4 + r] = sm[i][r];
  }
  __syncthreads();
  float inv[4][4];
#pragma unroll
  for (int i = 0; i < 4; ++i)
#pragma unroll
    for (int r = 0; r < 4; ++r) {
      int row = i * 16 + quad * 4 + r;
      inv[i][r] =
          1.0f / (red[0][row] + red[1][row] + red[2][row] + red[3][row]);
    }

  // ---- pack P to bf16 pairs (frees the fp32 S accumulators) ----
  unsigned pk[4][8][2];
#pragma unroll
  for (int i = 0; i < 4; ++i)
#pragma unroll
    for (int j = 0; j < 8; ++j)
#pragma unroll
      for (int rp = 0; rp < 2; ++rp) {
        float p0 = acc[i][j][2 * rp] * inv[i][2 * rp];
        float p1 = acc[i][j][2 * rp + 1] * inv[i][2 * rp + 1];
        pk[i][j][rp] = (unsigned)f2bf(p0) | ((unsigned)f2bf(p1) << 16);
      }

  // ---- phase PV: O[64 q, 512 d] = P V ----
  u16* lP = lds;         // 16KB: P-chunk [64 rows][128 n], swizzled
  u16* lV = lds + 8192;  // 32KB: V-stage [512 d][32 n]
  f32x4 o[4][8] = {};
  for (int ks = 0; ks < 16; ++ks) {
    __syncthreads();  // prev chunk/stage reads done
    if ((ks & 3) == 0 && wave == (ks >> 2)) {
      // wave c writes its P chunk: 16B-chunk col c' = cq ^ (row&15)
#pragma unroll
      for (int i = 0; i < 4; ++i)
#pragma unroll
        for (int j = 0; j < 8; ++j)
#pragma unroll
          for (int rp = 0; rp < 2; ++rp) {
            unsigned v = pk[i][j][rp];
#pragma unroll
            for (int hh = 0; hh < 2; ++hh) {
              int row = i * 16 + quad * 4 + rp * 2 + hh;
              int col = j * 16 + l16;
              int cc = (col >> 3) ^ (row & 15);
              lP[row * 128 + cc * 8 + (col & 7)] =
                  (u16)(hh ? (v >> 16) : (v & 0xffff));
            }
          }
    }
#pragma unroll
    for (int g = 0; g < 4; ++g)
      stage_tile(lV + g * 4096, Vb + (size_t)(g * 128) * 8192 + ks * 32, 8192,
                 wave, lane);
    __syncthreads();
    int cq = (ks & 3) * 4 + quad;
    bf16x8 pa[4];
#pragma unroll
    for (int i = 0; i < 4; ++i) {
      int row = i * 16 + l16;
      int cc = cq ^ (row & 15);
      pa[i] = *(const bf16x8*)(lP + row * 128 + cc * 8);
    }
#pragma unroll
    for (int jj = 0; jj < 8; ++jj) {
      bf16x8 vb = ldsfrag(lV, wave * 128 + jj * 16 + l16, quad);
#pragma unroll
      for (int i = 0; i < 4; ++i) o[i][jj] = mfma16(pa[i], vb, o[i][jj]);
    }
  }

  // ---- epilogue: out[(b*512+q)*4096 + h*512 + d] ----
  float* op = out + (size_t)b * 512 * 4096 + (size_t)h * 512;
#pragma unroll
  for (int i = 0; i < 4; ++i)
#pragma unroll
    for (int jj = 0; jj < 8; ++jj) {
      int d = wave * 128 + jj * 16 + l16;
#pragma unroll
      for (int r = 0; r < 4; ++r) {
        int q = q0 + i * 16 + quad * 4 + r;
        op[(size_t)q * 4096 + d] = o[i][jj][r];
      }
    }
}

// ---------------------------------------------------------------------------
extern "C" void kernel_launch(void* const* d_in, const int* in_sizes, int n_in,
                              void* d_out, int out_size, void* d_ws,
                              size_t ws_size, hipStream_t stream) {
  const float* x = (const float*)d_in[0];   // [16,512,512]  = [8192,512]
  const float* wq = (const float*)d_in[1];  // [512,4096]
  const float* wk = (const float*)d_in[2];
  const float* wv = (const float*)d_in[3];
  float* out = (float*)d_out;               // [16,512,4096]
  char* ws = (char*)d_ws;

  const size_t MB = 1024ull * 1024ull;
  u16* XHI = (u16*)(ws + 0 * MB);    // [8192,512] bf16 hi      8MB
  u16* XLO = (u16*)(ws + 8 * MB);    //                         8MB
  u16* WQH = (u16*)(ws + 16 * MB);   // wq split, orig layout   4MB
  u16* WQL = (u16*)(ws + 20 * MB);
  u16* WKH = (u16*)(ws + 24 * MB);
  u16* WKL = (u16*)(ws + 28 * MB);
  u16* WVTH = (u16*)(ws + 32 * MB);  // wv^T [4096,512]         4MB
  u16* WVTL = (u16*)(ws + 36 * MB);
  u16* MPH = (u16*)(ws + 40 * MB);   // M' = Wk Wq^T [8,512,512] 4MB
  u16* MPL = (u16*)(ws + 44 * MB);
  u16* THI = (u16*)(ws + 48 * MB);   // T = X M'^T [8,8192,512] 64MB
  u16* TLO = (u16*)(ws + 112 * MB);  //                         64MB
  u16* VT = (u16*)(ws + 176 * MB);   // V^T [4096,8192] bf16    64MB
  // total ws used: 240MB

  // --- prep ---
  split_hl_kernel<<<4096, 256, 0, stream>>>(x, XHI, XLO, 1048576);
  split_hl_kernel<<<2048, 256, 0, stream>>>(wq, WQH, WQL, 524288);
  split_hl_kernel<<<2048, 256, 0, stream>>>(wk, WKH, WKL, 524288);
  transpose_split_w<<<dim3(128, 16), dim3(32, 8), 0, stream>>>(wv, WVTH, WVTL);

  // --- M'_h = Wk_h Wq_h^T : [512,512] per head, x3 split, hi/lo out ---
  gemm_bt<1, 2, 0><<<dim3(4, 4, 8), 256, 0, stream>>>(
      WKH, WKL, WQH, WQL, MPH, MPL, 4096, 4096, 512, 512,
      /*aH*/ 0, /*aB*/ 512, /*bH*/ 0, /*bB*/ 512, /*cH*/ 0, /*cB*/ 262144);

  // --- T_h = X M'_h^T : [8192,512] per head, x3, hi/lo out.
  //     GRID=1: consecutive blocks share the X m-slice; head->XCD stable
  //     so the 4MB M' stays L2-resident per XCD. ---
  gemm_bt<1, 2, 1><<<dim3(4, 8, 64), 256, 0, stream>>>(
      XHI, XLO, MPH, MPL, THI, TLO, 512, 512, 512, 512,
      0, 0, /*bH*/ 262144, 0, /*cH*/ 4194304, 0);

  // --- V^T = Wv^T X^T : [4096 d, 8192 s], plain bf16.
  //     GRID=2: consecutive blocks share the X n-slice; d-tile->XCD stable
  //     so each XCD's 512KB WVT slice stays L2-resident. ---
  gemm_bt<0, 1, 2><<<dim3(32, 64, 1), 256, 0, stream>>>(
      WVTH, WVTH, XHI, XHI, VT, nullptr, 512, 512, 8192, 512,
      0, 0, 0, 0, 0, 0);

  // --- fused logits+softmax+PV: grid (q-tile, h*16+b); q->XCD stable,
  //     X_b reused across the 8 heads from L2. ---
  attn_fused<<<dim3(8, 128), 256, 0, stream>>>(THI, TLO, XHI, XLO, VT, out);
}

// Round 3
// 720.880 us; speedup vs baseline: 1.1169x; 1.1169x over previous
//
#include <hip/hip_runtime.h>

// ---------------------------------------------------------------------------
// MultiHead_BlockAttention: out[b,s,h*512+d] = softmax(X M_h X^T) (X Wv_h)
//   M'_h = Wk_h Wq_h^T (per head, contracted over head-dim), T_h = X M'_h^T,
//   logits = T X^T.  Precision: bf16 hi/lo x3-split on the logit path.
// R3: XCD-locality grids. attn_fused: L = b*64+q*8+h so XCD(=L%8)=h owns one
//     head, X_b/V_hb L2-resident. T-GEMM: L = h+8*(n+4*m) so M'_h resident.
// ---------------------------------------------------------------------------

typedef unsigned short u16;
typedef __bf16 bf16x8 __attribute__((ext_vector_type(8)));
typedef unsigned short u16x4 __attribute__((ext_vector_type(4)));
typedef float f32x4 __attribute__((ext_vector_type(4)));

typedef __attribute__((address_space(1))) void gvoid_t;
typedef __attribute__((address_space(3))) void svoid_t;

__device__ __forceinline__ u16 f2bf(float f) {
  unsigned u = __float_as_uint(f);
  u = (u + 0x7fffu + ((u >> 16) & 1u)) >> 16;  // RTN-even
  return (u16)u;
}
__device__ __forceinline__ float bf2f(u16 h) {
  return __uint_as_float(((unsigned)h) << 16);
}

__device__ __forceinline__ f32x4 mfma16(bf16x8 a, bf16x8 b, f32x4 c) {
  return __builtin_amdgcn_mfma_f32_16x16x32_bf16(a, b, c, 0, 0, 0);
}

// ---------------- prep: fp32 -> bf16 hi/lo split (same layout) -------------
__global__ __launch_bounds__(256) void split_hl_kernel(
    const float* __restrict__ in, u16* __restrict__ hi, u16* __restrict__ lo,
    int n4) {
  int i = blockIdx.x * 256 + threadIdx.x;
  if (i >= n4) return;
  float4 v = ((const float4*)in)[i];
  float vv[4] = {v.x, v.y, v.z, v.w};
  u16x4 h, l;
#pragma unroll
  for (int j = 0; j < 4; ++j) {
    u16 hh = f2bf(vv[j]);
    h[j] = hh;
    l[j] = f2bf(vv[j] - bf2f(hh));
  }
  ((u16x4*)hi)[i] = h;
  ((u16x4*)lo)[i] = l;
}

// ---------------- prep: transpose [512,4096] -> [4096,512] + split ---------
__global__ __launch_bounds__(256) void transpose_split_w(
    const float* __restrict__ in, u16* __restrict__ hi, u16* __restrict__ lo) {
  __shared__ float t[32][33];
  int d0 = blockIdx.x * 32, f0 = blockIdx.y * 32;
  int tx = threadIdx.x, ty = threadIdx.y;  // blockDim = (32,8)
#pragma unroll
  for (int r = 0; r < 4; ++r)
    t[ty + r * 8][tx] = in[(size_t)(f0 + ty + r * 8) * 4096 + d0 + tx];
  __syncthreads();
#pragma unroll
  for (int r = 0; r < 4; ++r) {
    float v = t[tx][ty + r * 8];  // = in[f0+tx][d0+ty+r*8]
    int d = d0 + ty + r * 8, f = f0 + tx;
    u16 h = f2bf(v);
    size_t idx = (size_t)d * 512 + f;
    hi[idx] = h;
    lo[idx] = f2bf(v - bf2f(h));
  }
}

// ---------------- LDS staging helpers (XOR-swizzled 16B chunks) ------------
// tile layout [rows][32 k] bf16; chunk (m,cq) stored at col c' = cq^((m>>1)&3)
__device__ __forceinline__ void stage_tile(u16* ldsTile, const u16* g0, int ld,
                                           int wave, int lane) {
#pragma unroll
  for (int r = 0; r < 2; ++r) {
    int p = r * 256 + wave * 64 + lane;  // LDS chunk position (128 rows x 4)
    int m = p >> 2;
    int cq = (p & 3) ^ ((m >> 1) & 3);   // global chunk col
    const u16* g = g0 + (size_t)m * ld + cq * 8;
    u16* l = ldsTile + (size_t)(r * 256 + wave * 64) * 8;  // wave-uniform
    __builtin_amdgcn_global_load_lds((gvoid_t*)g, (svoid_t*)l, 16, 0, 0);
  }
}

__device__ __forceinline__ void stage64(u16* ldsTile, const u16* g0, int ld,
                                        int wave, int lane) {
  int p = wave * 64 + lane;  // 64 rows x 4 chunks = 256
  int m = p >> 2;
  int cq = (p & 3) ^ ((m >> 1) & 3);
  const u16* g = g0 + (size_t)m * ld + cq * 8;
  u16* l = ldsTile + (size_t)(wave * 64) * 8;
  __builtin_amdgcn_global_load_lds((gvoid_t*)g, (svoid_t*)l, 16, 0, 0);
}

__device__ __forceinline__ bf16x8 ldsfrag(const u16* tile, int row, int quad) {
  int c = quad ^ ((row >> 1) & 3);
  return *(const bf16x8*)(tile + row * 32 + c * 8);
}

// ---------------- GEMM core: C[m][n] = sum_k A[m][k] * B[n][k] -------------
// GRID 0: (x=n0, y=m0, z=hb16). GRID 2: (x=m0, y=n0).
// GRID 3: 1D, L = h + 8*(n + 4*m) -> XCD(h) keeps its B-head slice resident.
// OMODE: 0 fp32; 1 bf16; 2 hi/lo bf16.
template <int SPLIT, int OMODE, int GRID>
__global__ __launch_bounds__(256, 2) void gemm_bt(
    const u16* __restrict__ Ah, const u16* __restrict__ Al,
    const u16* __restrict__ Bh, const u16* __restrict__ Bl,
    void* __restrict__ C0, void* __restrict__ C1, int lda, int ldb, int ldc,
    int K, size_t aH, size_t aB, size_t bH, size_t bB, size_t cH, size_t cB) {
  __shared__ __align__(16) u16 lds[(SPLIT ? 4 : 2) * 4096];
  u16* lAh = lds;
  u16* lAl = SPLIT ? (lds + 4096) : lds;
  u16* lBh = lds + (SPLIT ? 8192 : 4096);
  u16* lBl = SPLIT ? (lds + 12288) : lds;

  int m0, n0;
  size_t aOff, bOff, cOff;
  if (GRID == 0) {
    int zh = blockIdx.z >> 4, zb = blockIdx.z & 15;
    m0 = blockIdx.y * 128;
    n0 = blockIdx.x * 128;
    aOff = zh * aH + zb * aB;
    bOff = zh * bH + zb * bB;
    cOff = zh * cH + zb * cB;
  } else if (GRID == 2) {
    m0 = blockIdx.x * 128;
    n0 = blockIdx.y * 128;
    aOff = 0;
    bOff = 0;
    cOff = 0;
  } else {  // GRID 3
    int L = blockIdx.x;
    int hh = L & 7, rest = L >> 3;
    int n = rest & 3, m = rest >> 2;
    m0 = m * 128;
    n0 = n * 128;
    aOff = 0;
    bOff = hh * bH;
    cOff = hh * cH;
  }
  Ah += aOff;
  Al += aOff;
  Bh += bOff;
  Bl += bOff;

  const int tid = threadIdx.x;
  const int wave = tid >> 6, lane = tid & 63;
  const int quad = lane >> 4, l16 = lane & 15;
  const int wm = (wave >> 1) * 64, wn = (wave & 1) * 64;

  f32x4 acc[4][4] = {};

  for (int k0 = 0; k0 < K; k0 += 32) {
    stage_tile(lAh, Ah + (size_t)m0 * lda + k0, lda, wave, lane);
    if (SPLIT) stage_tile(lAl, Al + (size_t)m0 * lda + k0, lda, wave, lane);
    stage_tile(lBh, Bh + (size_t)n0 * ldb + k0, ldb, wave, lane);
    if (SPLIT) stage_tile(lBl, Bl + (size_t)n0 * ldb + k0, ldb, wave, lane);
    __syncthreads();

    bf16x8 a_h[4], a_l[4], b_h[4], b_l[4];
#pragma unroll
    for (int i = 0; i < 4; ++i) {
      a_h[i] = ldsfrag(lAh, wm + i * 16 + l16, quad);
      b_h[i] = ldsfrag(lBh, wn + i * 16 + l16, quad);
      if (SPLIT) {
        a_l[i] = ldsfrag(lAl, wm + i * 16 + l16, quad);
        b_l[i] = ldsfrag(lBl, wn + i * 16 + l16, quad);
      }
    }
#pragma unroll
    for (int i = 0; i < 4; ++i)
#pragma unroll
      for (int j = 0; j < 4; ++j) {
        acc[i][j] = mfma16(a_h[i], b_h[j], acc[i][j]);
        if (SPLIT) {
          acc[i][j] = mfma16(a_h[i], b_l[j], acc[i][j]);
          acc[i][j] = mfma16(a_l[i], b_h[j], acc[i][j]);
        }
      }
    __syncthreads();
  }

  // epilogue: C/D layout col = lane&15, row = quad*4 + reg
#pragma unroll
  for (int i = 0; i < 4; ++i) {
#pragma unroll
    for (int j = 0; j < 4; ++j) {
      int col = n0 + wn + j * 16 + l16;
#pragma unroll
      for (int r = 0; r < 4; ++r) {
        int row = m0 + wm + i * 16 + quad * 4 + r;
        size_t idx = cOff + (size_t)row * ldc + col;
        float v = acc[i][j][r];
        if (OMODE == 0) {
          ((float*)C0)[idx] = v;
        } else if (OMODE == 1) {
          ((u16*)C0)[idx] = f2bf(v);
        } else {
          u16 h = f2bf(v);
          ((u16*)C0)[idx] = h;
          ((u16*)C1)[idx] = f2bf(v - bf2f(h));
        }
      }
    }
  }
}

// ---------------- fused logits + softmax + PV (flash-style) ----------------
// Block = (q-tile 64 rows, one (h,b)). 4 waves; wave w owns key/dim slice
// [w*128, w*128+128). S = T X^T (x3 split) in 4x8 acc frags; cross-wave
// row max/sum via LDS; P chunked 16KB through LDS into PV (V staged 32KB/k).
// Grid 1D: L = b*64 + q*8 + h  => XCD = L%8 = h (one head per XCD; X_b and
// V_hb stay L2-resident across the 8 adjacent q-blocks).
__global__ __launch_bounds__(256, 2) void attn_fused(
    const u16* __restrict__ Th, const u16* __restrict__ Tl,
    const u16* __restrict__ Xh, const u16* __restrict__ Xl,
    const u16* __restrict__ Vt, float* __restrict__ out) {
  __shared__ __align__(16) u16 lds[36864];  // 72KB
  __shared__ float red[4][64];
  const int L = blockIdx.x;
  const int b = L >> 6, rr6 = L & 63;
  const int h = rr6 & 7, q0 = (rr6 >> 3) * 64;
  const int tid = threadIdx.x, wave = tid >> 6, lane = tid & 63;
  const int quad = lane >> 4, l16 = lane & 15;

  const u16* Ath =
      Th + (size_t)h * 4194304 + (size_t)b * 262144 + (size_t)q0 * 512;
  const u16* Atl =
      Tl + (size_t)h * 4194304 + (size_t)b * 262144 + (size_t)q0 * 512;
  const u16* Bxh = Xh + (size_t)b * 262144;
  const u16* Bxl = Xl + (size_t)b * 262144;
  const u16* Vb = Vt + (size_t)h * 512 * 8192 + (size_t)b * 512;

  u16* lAh = lds;          // 2048 u16 (4KB)
  u16* lAl = lds + 2048;   // 4KB
  u16* lBh = lds + 4096;   // 16384 u16 (32KB)
  u16* lBl = lds + 20480;  // 32KB

  f32x4 acc[4][8] = {};

  // ---- phase S: logits ----
  for (int k0 = 0; k0 < 512; k0 += 32) {
    stage64(lAh, Ath + k0, 512, wave, lane);
    stage64(lAl, Atl + k0, 512, wave, lane);
#pragma unroll
    for (int g = 0; g < 4; ++g) {
      stage_tile(lBh + g * 4096, Bxh + (size_t)(g * 128) * 512 + k0, 512, wave,
                 lane);
      stage_tile(lBl + g * 4096, Bxl + (size_t)(g * 128) * 512 + k0, 512, wave,
                 lane);
    }
    __syncthreads();
    bf16x8 a_h[4], a_l[4];
#pragma unroll
    for (int i = 0; i < 4; ++i) {
      a_h[i] = ldsfrag(lAh, i * 16 + l16, quad);
      a_l[i] = ldsfrag(lAl, i * 16 + l16, quad);
    }
#pragma unroll
    for (int j = 0; j < 8; ++j) {
      int br = wave * 128 + j * 16 + l16;
      bf16x8 b_h = ldsfrag(lBh, br, quad);
      bf16x8 b_l = ldsfrag(lBl, br, quad);
#pragma unroll
      for (int i = 0; i < 4; ++i) {
        acc[i][j] = mfma16(a_h[i], b_h, acc[i][j]);
        acc[i][j] = mfma16(a_h[i], b_l, acc[i][j]);
        acc[i][j] = mfma16(a_l[i], b_h, acc[i][j]);
      }
    }
    __syncthreads();
  }

  // ---- softmax over full rows (512 cols across the 4 waves) ----
  // lane's rows: i*16 + quad*4 + r ; cols: wave*128 + j*16 + l16
  float mx[4][4];
#pragma unroll
  for (int i = 0; i < 4; ++i)
#pragma unroll
    for (int r = 0; r < 4; ++r) {
      float m = acc[i][0][r];
#pragma unroll
      for (int j = 1; j < 8; ++j) m = fmaxf(m, acc[i][j][r]);
#pragma unroll
      for (int o = 1; o < 16; o <<= 1) m = fmaxf(m, __shfl_xor(m, o));
      mx[i][r] = m;
    }
  if (l16 == 0) {
#pragma unroll
    for (int i = 0; i < 4; ++i)
#pragma unroll
      for (int r = 0; r < 4; ++r) red[wave][i * 16 + quad * 4 + r] = mx[i][r];
  }
  __syncthreads();
#pragma unroll
  for (int i = 0; i < 4; ++i)
#pragma unroll
    for (int r = 0; r < 4; ++r) {
      int row = i * 16 + quad * 4 + r;
      mx[i][r] = fmaxf(fmaxf(red[0][row], red[1][row]),
                       fmaxf(red[2][row], red[3][row]));
    }
  __syncthreads();  // red reads done before sum round reuses it
  float sm[4][4];
#pragma unroll
  for (int i = 0; i < 4; ++i)
#pragma unroll
    for (int r = 0; r < 4; ++r) {
      float s = 0.f;
#pragma unroll
      for (int j = 0; j < 8; ++j) {
        float e = __expf(acc[i][j][r] - mx[i][r]);
        acc[i][j][r] = e;
        s += e;
      }
#pragma unroll
      for (int o = 1; o < 16; o <<= 1) s += __shfl_xor(s, o);
      sm[i][r] = s;
    }
  if (l16 == 0) {
#pragma unroll
    for (int i = 0; i < 4; ++i)
#pragma unroll
      for (int r = 0; r < 4; ++r) red[wave][i * 16 + quad * 4 + r] = sm[i][r];
  }
  __syncthreads();
  float inv[4][4];
#pragma unroll
  for (int i = 0; i < 4; ++i)
#pragma unroll
    for (int r = 0; r < 4; ++r) {
      int row = i * 16 + quad * 4 + r;
      inv[i][r] =
          1.0f / (red[0][row] + red[1][row] + red[2][row] + red[3][row]);
    }

  // ---- pack P to bf16 pairs (frees the fp32 S accumulators) ----
  unsigned pk[4][8][2];
#pragma unroll
  for (int i = 0; i < 4; ++i)
#pragma unroll
    for (int j = 0; j < 8; ++j)
#pragma unroll
      for (int rp = 0; rp < 2; ++rp) {
        float p0 = acc[i][j][2 * rp] * inv[i][2 * rp];
        float p1 = acc[i][j][2 * rp + 1] * inv[i][2 * rp + 1];
        pk[i][j][rp] = (unsigned)f2bf(p0) | ((unsigned)f2bf(p1) << 16);
      }

  // ---- phase PV: O[64 q, 512 d] = P V ----
  u16* lP = lds;         // 16KB: P-chunk [64 rows][128 n], swizzled
  u16* lV = lds + 8192;  // 32KB: V-stage [512 d][32 n]
  f32x4 o[4][8] = {};
  for (int ks = 0; ks < 16; ++ks) {
    __syncthreads();  // prev chunk/stage reads done
    if ((ks & 3) == 0 && wave == (ks >> 2)) {
      // wave c writes its P chunk: 16B-chunk col c' = cq ^ (row&15)
#pragma unroll
      for (int i = 0; i < 4; ++i)
#pragma unroll
        for (int j = 0; j < 8; ++j)
#pragma unroll
          for (int rp = 0; rp < 2; ++rp) {
            unsigned v = pk[i][j][rp];
#pragma unroll
            for (int hh = 0; hh < 2; ++hh) {
              int row = i * 16 + quad * 4 + rp * 2 + hh;
              int col = j * 16 + l16;
              int cc = (col >> 3) ^ (row & 15);
              lP[row * 128 + cc * 8 + (col & 7)] =
                  (u16)(hh ? (v >> 16) : (v & 0xffff));
            }
          }
    }
#pragma unroll
    for (int g = 0; g < 4; ++g)
      stage_tile(lV + g * 4096, Vb + (size_t)(g * 128) * 8192 + ks * 32, 8192,
                 wave, lane);
    __syncthreads();
    int cq = (ks & 3) * 4 + quad;
    bf16x8 pa[4];
#pragma unroll
    for (int i = 0; i < 4; ++i) {
      int row = i * 16 + l16;
      int cc = cq ^ (row & 15);
      pa[i] = *(const bf16x8*)(lP + row * 128 + cc * 8);
    }
#pragma unroll
    for (int jj = 0; jj < 8; ++jj) {
      bf16x8 vb = ldsfrag(lV, wave * 128 + jj * 16 + l16, quad);
#pragma unroll
      for (int i = 0; i < 4; ++i) o[i][jj] = mfma16(pa[i], vb, o[i][jj]);
    }
  }

  // ---- epilogue: out[(b*512+q)*4096 + h*512 + d] ----
  float* op = out + (size_t)b * 512 * 4096 + (size_t)h * 512;
#pragma unroll
  for (int i = 0; i < 4; ++i)
#pragma unroll
    for (int jj = 0; jj < 8; ++jj) {
      int d = wave * 128 + jj * 16 + l16;
#pragma unroll
      for (int r = 0; r < 4; ++r) {
        int q = q0 + i * 16 + quad * 4 + r;
        op[(size_t)q * 4096 + d] = o[i][jj][r];
      }
    }
}

// ---------------------------------------------------------------------------
extern "C" void kernel_launch(void* const* d_in, const int* in_sizes, int n_in,
                              void* d_out, int out_size, void* d_ws,
                              size_t ws_size, hipStream_t stream) {
  const float* x = (const float*)d_in[0];   // [16,512,512]  = [8192,512]
  const float* wq = (const float*)d_in[1];  // [512,4096]
  const float* wk = (const float*)d_in[2];
  const float* wv = (const float*)d_in[3];
  float* out = (float*)d_out;               // [16,512,4096]
  char* ws = (char*)d_ws;

  const size_t MB = 1024ull * 1024ull;
  u16* XHI = (u16*)(ws + 0 * MB);    // [8192,512] bf16 hi      8MB
  u16* XLO = (u16*)(ws + 8 * MB);    //                         8MB
  u16* WQH = (u16*)(ws + 16 * MB);   // wq split, orig layout   4MB
  u16* WQL = (u16*)(ws + 20 * MB);
  u16* WKH = (u16*)(ws + 24 * MB);
  u16* WKL = (u16*)(ws + 28 * MB);
  u16* WVTH = (u16*)(ws + 32 * MB);  // wv^T [4096,512]         4MB
  u16* WVTL = (u16*)(ws + 36 * MB);
  u16* MPH = (u16*)(ws + 40 * MB);   // M' = Wk Wq^T [8,512,512] 4MB
  u16* MPL = (u16*)(ws + 44 * MB);
  u16* THI = (u16*)(ws + 48 * MB);   // T = X M'^T [8,8192,512] 64MB
  u16* TLO = (u16*)(ws + 112 * MB);  //                         64MB
  u16* VT = (u16*)(ws + 176 * MB);   // V^T [4096,8192] bf16    64MB
  // total ws used: 240MB

  // --- prep ---
  split_hl_kernel<<<4096, 256, 0, stream>>>(x, XHI, XLO, 1048576);
  split_hl_kernel<<<2048, 256, 0, stream>>>(wq, WQH, WQL, 524288);
  split_hl_kernel<<<2048, 256, 0, stream>>>(wk, WKH, WKL, 524288);
  transpose_split_w<<<dim3(128, 16), dim3(32, 8), 0, stream>>>(wv, WVTH, WVTL);

  // --- M'_h = Wk_h Wq_h^T : [512,512] per head, x3 split, hi/lo out ---
  gemm_bt<1, 2, 0><<<dim3(4, 4, 8), 256, 0, stream>>>(
      WKH, WKL, WQH, WQL, MPH, MPL, 4096, 4096, 512, 512,
      /*aH*/ 0, /*aB*/ 512, /*bH*/ 0, /*bB*/ 512, /*cH*/ 0, /*cB*/ 262144);

  // --- V^T = Wv^T X^T : [4096 d, 8192 s], plain bf16.
  //     GRID=2: consecutive blocks share the X n-slice; 512KB WVT slice per
  //     XCD stays L2-resident. ---
  gemm_bt<0, 1, 2><<<dim3(32, 64, 1), 256, 0, stream>>>(
      WVTH, WVTH, XHI, XHI, VT, nullptr, 512, 512, 8192, 512,
      0, 0, 0, 0, 0, 0);

  // --- T_h = X M'_h^T : [8192,512] per head, x3, hi/lo out.
  //     GRID=3: L = h + 8*(n + 4*m) -> XCD = h; M'_h (1MB hi+lo) L2-resident,
  //     X m-slice reused across the 4 adjacent n-blocks. ---
  gemm_bt<1, 2, 3><<<2048, 256, 0, stream>>>(
      XHI, XLO, MPH, MPL, THI, TLO, 512, 512, 512, 512,
      0, 0, /*bH*/ 262144, 0, /*cH*/ 4194304, 0);

  // --- fused logits+softmax+PV: L = b*64 + q*8 + h -> XCD = h.
  //     Per XCD: one head; X_b (1MB) + V_hb (512KB) reused across the 8
  //     adjacent q-blocks; T read exactly once. ---
  attn_fused<<<1024, 256, 0, stream>>>(THI, TLO, XHI, XLO, VT, out);
}